// Round 3
// baseline (506.513 us; speedup 1.0000x reference)
//
#include <hip/hip_runtime.h>

namespace {
constexpr int Sc = 2048, Dc = 768, Hc = 12, Mc = 4096;

using fragb = __attribute__((ext_vector_type(8))) short;   // 8 bf16 (4 VGPRs)
using f32x4 = __attribute__((ext_vector_type(4))) float;   // MFMA C/D

#define MFMA16(A, B, C) __builtin_amdgcn_mfma_f32_16x16x32_bf16(A, B, C, 0, 0, 0)

// fp32 -> bf16 bits, round-to-nearest-even (used only for P in attention)
__device__ __forceinline__ unsigned short bf16rne(float f) {
  unsigned int u = __float_as_uint(f);
  return (unsigned short)((u + 0x7fffu + ((u >> 16) & 1u)) >> 16);
}
// truncation split: f ~= hi + lo, both bf16-truncated. ~5 VALU ops, no unions.
__device__ __forceinline__ void splitt(float f, unsigned short& h, unsigned short& l) {
  const unsigned int u = __float_as_uint(f);
  h = (unsigned short)(u >> 16);
  const float r = f - __uint_as_float(u & 0xffff0000u);
  l = (unsigned short)(__float_as_uint(r) >> 16);
}

// ---------------------------------------------------------------------------
// Y = X @ W^T (+bias), split-bf16 MFMA (hh + hl + lh), fp32 accumulate.
// 128x64 tile, BK=32, 256 threads (4 waves; wave w owns rows 32w..32w+31).
// AMODE: 0 = fp32 A source; 1 = bf16 hi/lo plane A source (pure copy staging).
// OMODE: 0 = planes [b,h,s,dk]; 1 = planes [b,h,dk,s] (V transposed);
//        2 = fp32 [M][D] + bias.
// ---------------------------------------------------------------------------
template <int AMODE, int OMODE>
__global__ __launch_bounds__(256, 4) void proj_kernel(
    const void* __restrict__ Asrc_h, const void* __restrict__ Asrc_l,
    const float* __restrict__ W, const float* __restrict__ bias,
    unsigned short* __restrict__ Oh, unsigned short* __restrict__ Ol,
    float* __restrict__ Ofp)
{
  const int tid = threadIdx.x;
  const int lane = tid & 63, w = tid >> 6;
  const int g = lane >> 4, l15 = lane & 15;
  const int m0 = blockIdx.x * 128, n0 = blockIdx.y * 64;

  // stride 40 bf16 = 80 B: rows 16B-aligned, near-uniform bank spread for b128
  __shared__ __align__(16) unsigned short Ah[128][40], Al[128][40];
  __shared__ __align__(16) unsigned short Bh[64][40],  Bl[64][40];

  f32x4 acc[2][4] = {};

  const int arow = tid >> 1;           // 0..127 (A staging row)
  const int acol = (tid & 1) * 16;     // 0 or 16
  const int brow = tid >> 2;           // 0..63  (B staging row)
  const int bcol = (tid & 3) * 8;      // 0,8,16,24

  for (int k0 = 0; k0 < Dc; k0 += 32) {
    // ---- load (+ cheap convert) before barrier ----
    unsigned short ah[16], al[16], bh[8], bl[8];
    if (AMODE == 0) {
      const float* ap = (const float*)Asrc_h + (size_t)(m0 + arow) * Dc + k0 + acol;
#pragma unroll
      for (int i = 0; i < 16; i += 4) {
        const float4 v = *(const float4*)(ap + i);
        splitt(v.x, ah[i+0], al[i+0]); splitt(v.y, ah[i+1], al[i+1]);
        splitt(v.z, ah[i+2], al[i+2]); splitt(v.w, ah[i+3], al[i+3]);
      }
    } else {
      const unsigned short* aph = (const unsigned short*)Asrc_h + (size_t)(m0 + arow) * Dc + k0 + acol;
      const unsigned short* apl = (const unsigned short*)Asrc_l + (size_t)(m0 + arow) * Dc + k0 + acol;
      *(uint4*)&ah[0] = *(const uint4*)(aph);
      *(uint4*)&ah[8] = *(const uint4*)(aph + 8);
      *(uint4*)&al[0] = *(const uint4*)(apl);
      *(uint4*)&al[8] = *(const uint4*)(apl + 8);
    }
    {
      const float* wp = W + (size_t)(n0 + brow) * Dc + k0 + bcol;
#pragma unroll
      for (int i = 0; i < 8; i += 4) {
        const float4 v = *(const float4*)(wp + i);
        splitt(v.x, bh[i+0], bl[i+0]); splitt(v.y, bh[i+1], bl[i+1]);
        splitt(v.z, bh[i+2], bl[i+2]); splitt(v.w, bh[i+3], bl[i+3]);
      }
    }
    __syncthreads();                  // previous tile's compute done
    *(uint4*)&Ah[arow][acol]     = *(uint4*)&ah[0];
    *(uint4*)&Ah[arow][acol + 8] = *(uint4*)&ah[8];
    *(uint4*)&Al[arow][acol]     = *(uint4*)&al[0];
    *(uint4*)&Al[arow][acol + 8] = *(uint4*)&al[8];
    *(uint4*)&Bh[brow][bcol]     = *(uint4*)&bh[0];
    *(uint4*)&Bl[brow][bcol]     = *(uint4*)&bl[0];
    __syncthreads();

    // ---- compute ----
    fragb bHf[4], bLf[4];
#pragma unroll
    for (int nb = 0; nb < 4; ++nb) {
      bHf[nb] = *(const fragb*)&Bh[nb * 16 + l15][8 * g];
      bLf[nb] = *(const fragb*)&Bl[nb * 16 + l15][8 * g];
    }
#pragma unroll
    for (int s = 0; s < 2; ++s) {
      const fragb aH = *(const fragb*)&Ah[32 * w + 16 * s + l15][8 * g];
      const fragb aL = *(const fragb*)&Al[32 * w + 16 * s + l15][8 * g];
#pragma unroll
      for (int nb = 0; nb < 4; ++nb) {
        acc[s][nb] = MFMA16(aH, bHf[nb], acc[s][nb]);
        acc[s][nb] = MFMA16(aH, bLf[nb], acc[s][nb]);
        acc[s][nb] = MFMA16(aL, bHf[nb], acc[s][nb]);
      }
    }
  }

  // ---- epilogue: C/D layout col = l15, row = 4g + r ----
#pragma unroll
  for (int s = 0; s < 2; ++s) {
    const int mrow = m0 + 32 * w + 16 * s + 4 * g;
    if (OMODE == 2) {
#pragma unroll
      for (int nb = 0; nb < 4; ++nb) {
        const int n = n0 + nb * 16 + l15;
        const float bv = bias[n];
#pragma unroll
        for (int r = 0; r < 4; ++r)
          Ofp[(size_t)(mrow + r) * Dc + n] = acc[s][nb][r] + bv;
      }
    } else {
#pragma unroll
      for (int nb = 0; nb < 4; ++nb) {
        const int n = n0 + nb * 16 + l15;
        const int hh = n >> 6, dk = n & 63;
#pragma unroll
        for (int r = 0; r < 4; ++r) {
          const int m = mrow + r;
          const int bb = m >> 11, ss = m & (Sc - 1);
          const size_t idx = (OMODE == 0)
              ? (((size_t)bb * Hc + hh) * Sc + ss) * 64 + dk
              : (((size_t)bb * Hc + hh) * 64 + dk) * Sc + ss;
          unsigned short h, l;
          splitt(acc[s][nb][r], h, l);
          Oh[idx] = h; Ol[idx] = l;
        }
      }
    }
  }
}

// ---------------------------------------------------------------------------
// Flash-style causal attention on split-bf16 MFMA (structure identical to the
// validated round-2 kernel; staging now pure plane copies, zero unpack VALU).
// Block = complementary 32-row Q-tile pair (t, 63-t). 256 threads / 4 waves;
// waves 0,1 -> tile t, waves 2,3 -> tile 63-t; each wave owns 16 Q rows.
// ---------------------------------------------------------------------------
__global__ __launch_bounds__(256, 3) void attn_kernel(
    const unsigned short* __restrict__ Qh, const unsigned short* __restrict__ Ql,
    const unsigned short* __restrict__ Kh, const unsigned short* __restrict__ Kl,
    const unsigned short* __restrict__ Vth, const unsigned short* __restrict__ Vtl,
    unsigned short* __restrict__ Aoh, unsigned short* __restrict__ Aol)
{
  const int tid = threadIdx.x;
  const int lane = tid & 63, w = tid >> 6;
  const int g = lane >> 4, l15 = lane & 15;
  const int t = blockIdx.x;                 // pair id 0..31
  const int bh = blockIdx.y;
  const int b = bh / Hc, h = bh % Hc;

  const int qtile = (w < 2) ? t : (63 - t);
  const int qbase = qtile * 32 + (w & 1) * 16;
  const int ktmax = (qbase + 15) >> 6;                 // last k-tile this wave needs
  const int NKT = ((Sc - 1 - 32 * t) >> 6) + 1;        // block loop count

  // stride 72 bf16 = 144 B: rows 16B-aligned
  __shared__ __align__(16) unsigned short Ks_h[64][72], Ks_l[64][72];
  __shared__ __align__(16) unsigned short Vt_h[64][72], Vt_l[64][72];
  __shared__ __align__(16) unsigned short Ps[64][72];

  // ---- Q fragments in registers (A-frag: row=l15, k=32c+8g+j) ----
  fragb qfh[2], qfl[2];
  {
    const unsigned short* qrh = Qh + ((size_t)bh * Sc + qbase + l15) * 64;
    const unsigned short* qrl = Ql + ((size_t)bh * Sc + qbase + l15) * 64;
#pragma unroll
    for (int c = 0; c < 2; ++c) {
      qfh[c] = *(const fragb*)(qrh + c * 32 + g * 8);
      qfl[c] = *(const fragb*)(qrl + c * 32 + g * 8);
    }
  }

  f32x4 oacc[4] = {};
  float m_run[4] = {-1e30f, -1e30f, -1e30f, -1e30f};
  float l_run[4] = {0.f, 0.f, 0.f, 0.f};

  const int srow = tid >> 2;          // K: key row / V: dk row
  const int scol = (tid & 3) * 16;    // K: dk offset / V: key offset (elements)

  for (int kt = 0; kt < NKT; ++kt) {
    const int k0 = kt * 64;
    // ---- issue global loads before barrier (pure copies) ----
    uint4 st[8];
    {
      const unsigned short* kph = Kh  + ((size_t)bh * Sc + k0 + srow) * 64 + scol;
      const unsigned short* kpl = Kl  + ((size_t)bh * Sc + k0 + srow) * 64 + scol;
      const unsigned short* vph = Vth + ((size_t)bh * 64 + srow) * Sc + k0 + scol;
      const unsigned short* vpl = Vtl + ((size_t)bh * 64 + srow) * Sc + k0 + scol;
      st[0] = *(const uint4*)(kph);  st[1] = *(const uint4*)(kph + 8);
      st[2] = *(const uint4*)(kpl);  st[3] = *(const uint4*)(kpl + 8);
      st[4] = *(const uint4*)(vph);  st[5] = *(const uint4*)(vph + 8);
      st[6] = *(const uint4*)(vpl);  st[7] = *(const uint4*)(vpl + 8);
    }
    __syncthreads();                  // all waves done with prev tile's LDS
    *(uint4*)&Ks_h[srow][scol]     = st[0];
    *(uint4*)&Ks_h[srow][scol + 8] = st[1];
    *(uint4*)&Ks_l[srow][scol]     = st[2];
    *(uint4*)&Ks_l[srow][scol + 8] = st[3];
    *(uint4*)&Vt_h[srow][scol]     = st[4];
    *(uint4*)&Vt_h[srow][scol + 8] = st[5];
    *(uint4*)&Vt_l[srow][scol]     = st[6];
    *(uint4*)&Vt_l[srow][scol + 8] = st[7];
    __syncthreads();

    if (kt <= ktmax) {                // wave-uniform branch
      // ---- S = Q K^T (3-term split) ----
      f32x4 sacc[4] = {};
#pragma unroll
      for (int c = 0; c < 2; ++c) {
#pragma unroll
        for (int kb = 0; kb < 4; ++kb) {
          const fragb kH = *(const fragb*)&Ks_h[kb * 16 + l15][c * 32 + g * 8];
          const fragb kL = *(const fragb*)&Ks_l[kb * 16 + l15][c * 32 + g * 8];
          sacc[kb] = MFMA16(qfh[c], kH, sacc[kb]);
          sacc[kb] = MFMA16(qfh[c], kL, sacc[kb]);
          sacc[kb] = MFMA16(qfl[c], kH, sacc[kb]);
        }
      }
      // ---- scale + causal mask + online softmax (rows in 16-lane groups) ----
      float p[4][4], mx[4];
#pragma unroll
      for (int r = 0; r < 4; ++r) {
        const int qrow = qbase + 4 * g + r;
#pragma unroll
        for (int kb = 0; kb < 4; ++kb) {
          const int kc = k0 + kb * 16 + l15;
          const float x = sacc[kb][r] * 0.125f;    // 1/sqrt(64)
          p[kb][r] = (kc > qrow) ? -1e30f : x;
        }
        mx[r] = fmaxf(fmaxf(p[0][r], p[1][r]), fmaxf(p[2][r], p[3][r]));
      }
#pragma unroll
      for (int off = 8; off > 0; off >>= 1)
#pragma unroll
        for (int r = 0; r < 4; ++r)
          mx[r] = fmaxf(mx[r], __shfl_xor(mx[r], off));
#pragma unroll
      for (int r = 0; r < 4; ++r) {
        const float mnew = fmaxf(m_run[r], mx[r]);
        const float alpha = __expf(m_run[r] - mnew);
        m_run[r] = mnew;
        float rs = 0.f;
#pragma unroll
        for (int kb = 0; kb < 4; ++kb) { p[kb][r] = __expf(p[kb][r] - mnew); rs += p[kb][r]; }
#pragma unroll
        for (int off = 8; off > 0; off >>= 1) rs += __shfl_xor(rs, off);
        l_run[r] = l_run[r] * alpha + rs;
#pragma unroll
        for (int db = 0; db < 4; ++db) oacc[db][r] *= alpha;
      }
      // ---- P -> LDS (own wave strip) ----
      const int strip = 16 * w;
#pragma unroll
      for (int kb = 0; kb < 4; ++kb)
#pragma unroll
        for (int r = 0; r < 4; ++r)
          Ps[strip + 4 * g + r][kb * 16 + l15] = bf16rne(p[kb][r]);
      // ---- O += P (Vh + Vl) ----
#pragma unroll
      for (int c = 0; c < 2; ++c) {
        const fragb pf = *(const fragb*)&Ps[strip + l15][c * 32 + g * 8];
#pragma unroll
        for (int db = 0; db < 4; ++db) {
          const fragb vH = *(const fragb*)&Vt_h[db * 16 + l15][c * 32 + g * 8];
          const fragb vL = *(const fragb*)&Vt_l[db * 16 + l15][c * 32 + g * 8];
          oacc[db] = MFMA16(pf, vH, oacc[db]);
          oacc[db] = MFMA16(pf, vL, oacc[db]);
        }
      }
    }
  }

  // ---- epilogue: normalize, write hi/lo planes of attended [B,S,D] ----
#pragma unroll
  for (int r = 0; r < 4; ++r) {
    const float rl = 1.0f / l_run[r];
    const int s = qbase + 4 * g + r;
    const size_t base = ((size_t)b * Sc + s) * Dc + h * 64 + l15;
#pragma unroll
    for (int db = 0; db < 4; ++db) {
      unsigned short hbits, lbits;
      splitt(oacc[db][r] * rl, hbits, lbits);
      Aoh[base + db * 16] = hbits;
      Aol[base + db * 16] = lbits;
    }
  }
}

}  // namespace

extern "C" void kernel_launch(void* const* d_in, const int* in_sizes, int n_in,
                              void* d_out, int out_size, void* d_ws, size_t ws_size,
                              hipStream_t stream) {
  const float* q  = (const float*)d_in[0];
  const float* k  = (const float*)d_in[1];
  const float* v  = (const float*)d_in[2];
  // d_in[3] = causal mask (bool) — structure known, not read
  const float* wq = (const float*)d_in[4];
  const float* wk = (const float*)d_in[5];
  const float* wv = (const float*)d_in[6];
  const float* wo = (const float*)d_in[7];
  const float* bo = (const float*)d_in[8];

  unsigned short* ws = (unsigned short*)d_ws;
  const size_t NQ = (size_t)Mc * Dc;        // 3,145,728 elements per plane
  unsigned short* Qh_  = ws + 0 * NQ;       // [b,h,s,dk] hi
  unsigned short* Ql_  = ws + 1 * NQ;       //            lo
  unsigned short* Kh_  = ws + 2 * NQ;
  unsigned short* Kl_  = ws + 3 * NQ;
  unsigned short* Vth_ = ws + 4 * NQ;       // [b,h,dk,s] hi
  unsigned short* Vtl_ = ws + 5 * NQ;       //            lo
  unsigned short* Ath_ = ws + 6 * NQ;       // [b,s,d]    hi
  unsigned short* Atl_ = ws + 7 * NQ;       //            lo   (50.3 MB total)

  const dim3 blk(256);
  const dim3 gproj(Mc / 128, Dc / 64);      // 32 x 12 = 384 blocks
  const dim3 gattn(32, 2 * Hc);             // 32 pairs x 24 (b,h)

  proj_kernel<0, 0><<<gproj, blk, 0, stream>>>(q, nullptr, wq, nullptr, Qh_, Ql_, nullptr);
  proj_kernel<0, 0><<<gproj, blk, 0, stream>>>(k, nullptr, wk, nullptr, Kh_, Kl_, nullptr);
  proj_kernel<0, 1><<<gproj, blk, 0, stream>>>(v, nullptr, wv, nullptr, Vth_, Vtl_, nullptr);
  attn_kernel<<<gattn, blk, 0, stream>>>(Qh_, Ql_, Kh_, Kl_, Vth_, Vtl_, Ath_, Atl_);
  proj_kernel<1, 2><<<gproj, blk, 0, stream>>>(Ath_, Atl_, wo, bo, nullptr, nullptr, (float*)d_out);
}

// Round 6
// 349.520 us; speedup vs baseline: 1.4492x; 1.4492x over previous
//
#include <hip/hip_runtime.h>

namespace {
constexpr int Sc = 2048, Dc = 768, Hc = 12, Mc = 4096;

using fragb = __attribute__((ext_vector_type(8))) short;   // 8 bf16 (4 VGPRs)
using f32x4 = __attribute__((ext_vector_type(4))) float;   // MFMA C/D

#define MFMA16(A, B, C) __builtin_amdgcn_mfma_f32_16x16x32_bf16(A, B, C, 0, 0, 0)

// fp32 -> bf16 bits, round-to-nearest-even (only for P in attention)
__device__ __forceinline__ unsigned short bf16rne(float f) {
  unsigned int u = __float_as_uint(f);
  return (unsigned short)((u + 0x7fffu + ((u >> 16) & 1u)) >> 16);
}
// truncation split: f ~= hi + lo (both bf16-truncated), ~5 VALU ops
__device__ __forceinline__ void splitt(float f, unsigned short& h, unsigned short& l) {
  const unsigned int u = __float_as_uint(f);
  h = (unsigned short)(u >> 16);
  const float r = f - __uint_as_float(u & 0xffff0000u);
  l = (unsigned short)(__float_as_uint(r) >> 16);
}
// async HBM->LDS DMA, 16 B per lane. g: per-lane global addr; l: wave-uniform LDS base.
__device__ __forceinline__ void gload16(const unsigned short* g, unsigned short* l) {
  __builtin_amdgcn_global_load_lds(
      (const __attribute__((address_space(1))) void*)g,
      (__attribute__((address_space(3))) void*)l, 16, 0, 0);
}

// ---------------------------------------------------------------------------
// fp32 -> (hi, lo) bf16 planes. 8 elems/thread, fully coalesced.
// ---------------------------------------------------------------------------
__global__ __launch_bounds__(256) void split_kernel(
    const float* __restrict__ src, unsigned short* __restrict__ h,
    unsigned short* __restrict__ l, int n8)
{
  const int i = blockIdx.x * 256 + threadIdx.x;
  if (i >= n8) return;
  const float4 v0 = *(const float4*)(src + (size_t)i * 8);
  const float4 v1 = *(const float4*)(src + (size_t)i * 8 + 4);
  const float x[8] = {v0.x, v0.y, v0.z, v0.w, v1.x, v1.y, v1.z, v1.w};
  unsigned short hh[8], ll[8];
#pragma unroll
  for (int j = 0; j < 8; ++j) splitt(x[j], hh[j], ll[j]);
  *(uint4*)&h[(size_t)i * 8] = *(const uint4*)&hh[0];
  *(uint4*)&l[(size_t)i * 8] = *(const uint4*)&ll[0];
}

// ---------------------------------------------------------------------------
// Y = Xplanes @ W^T (+bias), split-bf16 MFMA (hh + hl + lh), fp32 accumulate.
// 128x64 tile, BK=32, 256 threads / 4 waves. A staged via global_load_lds
// (zero VALU); W (fp32) split in-register (8 floats/thread/tile).
// OMODE: 0 = planes [b,h,s,dk]; 1 = planes [b,h,dk,s]; 2 = fp32 [M][D]+bias.
// ---------------------------------------------------------------------------
template <int OMODE>
__global__ __launch_bounds__(256, 4) void proj_kernel(
    const unsigned short* __restrict__ Xh, const unsigned short* __restrict__ Xl,
    const float* __restrict__ W, const float* __restrict__ bias,
    unsigned short* __restrict__ Oh, unsigned short* __restrict__ Ol,
    float* __restrict__ Ofp)
{
  const int tid = threadIdx.x;
  const int lane = tid & 63, w = tid >> 6;
  const int g = lane >> 4, l15 = lane & 15;
  const int lrow = lane >> 2, lslot = lane & 3;   // staging: row-in-chunk, 16B slot
  const int m0 = blockIdx.x * 128, n0 = blockIdx.y * 64;

  // flat LDS (ushort): Ah[0,4096) Al[4096,8192) Bh[8192,10240) Bl[10240,12288)
  __shared__ __align__(16) unsigned short sb[12288];

  f32x4 acc[2][4] = {};

  const int brow = tid >> 2;           // 0..63 (B staging row)
  const int bcol = (tid & 3) * 8;      // 0,8,16,24 (k elems)
  const float* wp0 = W + (size_t)(n0 + brow) * Dc + bcol;

  for (int k0 = 0; k0 < Dc; k0 += 32) {
    // ---- B: fp32 load + split into 8 packed u32 (tiny live range) ----
    unsigned int bpk[4], lpk[4];
    {
      const float* wp = wp0 + k0;
      const float4 v0 = *(const float4*)wp;
      const float4 v1 = *(const float4*)(wp + 4);
      const float x[8] = {v0.x, v0.y, v0.z, v0.w, v1.x, v1.y, v1.z, v1.w};
#pragma unroll
      for (int j = 0; j < 4; ++j) {
        unsigned short h0, l0, h1, l1;
        splitt(x[2*j], h0, l0); splitt(x[2*j+1], h1, l1);
        bpk[j] = (unsigned int)h0 | ((unsigned int)h1 << 16);
        lpk[j] = (unsigned int)l0 | ((unsigned int)l1 << 16);
      }
    }
    __syncthreads();                   // prev tile's compute done
    // ---- A: pure DMA, wave w stages chunks 2w, 2w+1 of each plane ----
#pragma unroll
    for (int i = 0; i < 2; ++i) {
      const int q = 2 * w + i;         // 1KB chunk = 16 rows
      const size_t goff = (size_t)(m0 + q * 16 + lrow) * Dc + k0 + lslot * 8;
      gload16(Xh + goff, &sb[q * 512]);
      gload16(Xl + goff, &sb[4096 + q * 512]);
    }
    // ---- B: LDS write ----
    *(uint4*)&sb[8192  + brow * 32 + bcol] = *(const uint4*)&bpk[0];
    *(uint4*)&sb[10240 + brow * 32 + bcol] = *(const uint4*)&lpk[0];
    __syncthreads();                   // drains vmcnt + lgkmcnt

    // ---- compute: 24 MFMA ----
    fragb bHf[4], bLf[4];
#pragma unroll
    for (int nb = 0; nb < 4; ++nb) {
      bHf[nb] = *(const fragb*)&sb[8192  + (nb * 16 + l15) * 32 + 8 * g];
      bLf[nb] = *(const fragb*)&sb[10240 + (nb * 16 + l15) * 32 + 8 * g];
    }
#pragma unroll
    for (int s = 0; s < 2; ++s) {
      const fragb aH = *(const fragb*)&sb[(32 * w + 16 * s + l15) * 32 + 8 * g];
      const fragb aL = *(const fragb*)&sb[4096 + (32 * w + 16 * s + l15) * 32 + 8 * g];
#pragma unroll
      for (int nb = 0; nb < 4; ++nb) {
        acc[s][nb] = MFMA16(aH, bHf[nb], acc[s][nb]);
        acc[s][nb] = MFMA16(aH, bLf[nb], acc[s][nb]);
        acc[s][nb] = MFMA16(aL, bHf[nb], acc[s][nb]);
      }
    }
  }

  // ---- epilogue ----
  if constexpr (OMODE == 2) {
#pragma unroll
    for (int s = 0; s < 2; ++s) {
      const int mrow = m0 + 32 * w + 16 * s + 4 * g;
#pragma unroll
      for (int nb = 0; nb < 4; ++nb) {
        const int n = n0 + nb * 16 + l15;
        const float bv = bias[n];
#pragma unroll
        for (int r = 0; r < 4; ++r)
          Ofp[(size_t)(mrow + r) * Dc + n] = acc[s][nb][r] + bv;
      }
    }
  } else {
    // LDS transpose -> coalesced uint4 dumps (hi pass, then lo pass)
    const int hsel = n0 >> 6;            // one head per n-tile
    const int bb = m0 >> 11;             // batch (128-row tile within one b)
    const int sl0 = m0 & (Sc - 1);
#pragma unroll
    for (int pass = 0; pass < 2; ++pass) {
      __syncthreads();                   // sb free (compute / prev pass done)
#pragma unroll
      for (int s = 0; s < 2; ++s)
#pragma unroll
        for (int nb = 0; nb < 4; ++nb)
#pragma unroll
          for (int r = 0; r < 4; ++r) {
            unsigned short hv, lv;
            splitt(acc[s][nb][r], hv, lv);
            const int srow = 32 * w + 16 * s + 4 * g + r;   // token-local
            const int dk = nb * 16 + l15;
            if (OMODE == 0) sb[srow * 64 + dk] = pass ? lv : hv;
            else            sb[dk * 128 + srow] = pass ? lv : hv;
          }
      __syncthreads();
      unsigned short* dst = pass ? Ol : Oh;
#pragma unroll
      for (int c2 = tid; c2 < 1024; c2 += 256) {
        size_t gidx;
        if (OMODE == 0) {               // [b,h,s,dk]
          const int sl = c2 >> 3, off = (c2 & 7) * 8;
          gidx = (((size_t)bb * Hc + hsel) * Sc + sl0 + sl) * 64 + off;
        } else {                        // [b,h,dk,s]
          const int dk = c2 >> 4, off = (c2 & 15) * 8;
          gidx = (((size_t)bb * Hc + hsel) * 64 + dk) * Sc + sl0 + off;
        }
        *(uint4*)&dst[gidx] = *(const uint4*)&sb[c2 * 8];
      }
    }
  }
}

// ---------------------------------------------------------------------------
// Flash-style causal attention, split-bf16 MFMA. K/V staging is pure
// global_load_lds DMA (wave w stages plane w). Math identical to round 2/3.
// ---------------------------------------------------------------------------
__global__ __launch_bounds__(256, 3) void attn_kernel(
    const unsigned short* __restrict__ Qh, const unsigned short* __restrict__ Ql,
    const unsigned short* __restrict__ Kh, const unsigned short* __restrict__ Kl,
    const unsigned short* __restrict__ Vth, const unsigned short* __restrict__ Vtl,
    unsigned short* __restrict__ Aoh, unsigned short* __restrict__ Aol)
{
  const int tid = threadIdx.x;
  const int lane = tid & 63, w = tid >> 6;
  const int g = lane >> 4, l15 = lane & 15;
  const int lrow = lane >> 2, lslot = lane & 3;
  const int t = blockIdx.x;                 // pair id 0..31
  const int bh = blockIdx.y;
  const int b = bh / Hc, h = bh % Hc;

  const int qtile = (w < 2) ? t : (63 - t);
  const int qbase = qtile * 32 + (w & 1) * 16;
  const int ktmax = (qbase + 15) >> 6;
  const int NKT = ((Sc - 1 - 32 * t) >> 6) + 1;

  // flat LDS (ushort): Kh[0) Kl[4096) Vh[8192) Vl[12288) Ps[16384,20992)
  // K planes: [2 dk-chunks][64 keys][32]; V planes: [2 s-chunks][64 dk][32]
  __shared__ __align__(16) unsigned short sbuf[20992];

  // wave w stages plane w for the whole block
  const unsigned short* gbase;
  if      (w == 0) gbase = Kh  + (size_t)bh * Sc * 64;
  else if (w == 1) gbase = Kl  + (size_t)bh * Sc * 64;
  else if (w == 2) gbase = Vth + (size_t)bh * 64 * Sc;
  else             gbase = Vtl + (size_t)bh * 64 * Sc;
  const bool isK = (w < 2);

  // ---- Q fragments in registers ----
  fragb qfh[2], qfl[2];
  {
    const unsigned short* qrh = Qh + ((size_t)bh * Sc + qbase + l15) * 64;
    const unsigned short* qrl = Ql + ((size_t)bh * Sc + qbase + l15) * 64;
#pragma unroll
    for (int c = 0; c < 2; ++c) {
      qfh[c] = *(const fragb*)(qrh + c * 32 + g * 8);
      qfl[c] = *(const fragb*)(qrl + c * 32 + g * 8);
    }
  }

  f32x4 oacc[4] = {};
  float m_run[4] = {-1e30f, -1e30f, -1e30f, -1e30f};
  float l_run[4] = {0.f, 0.f, 0.f, 0.f};

  for (int kt = 0; kt < NKT; ++kt) {
    const int k0 = kt * 64;
    __syncthreads();                  // all waves done reading prev tile
#pragma unroll
    for (int q = 0; q < 8; ++q) {     // 8 x 1KB chunks = wave's plane
      const int cc = q >> 2, rb = (q & 3) * 16;
      const size_t off = isK
          ? ((size_t)(k0 + rb + lrow) * 64 + cc * 32 + lslot * 8)
          : ((size_t)(rb + lrow) * Sc + k0 + cc * 32 + lslot * 8);
      gload16(gbase + off, &sbuf[w * 4096 + q * 512]);
    }
    __syncthreads();                  // vmcnt drained before barrier

    if (kt <= ktmax) {                // wave-uniform
      // ---- S = Q K^T (3-term split) ----
      f32x4 sacc[4] = {};
#pragma unroll
      for (int c = 0; c < 2; ++c) {
#pragma unroll
        for (int kb = 0; kb < 4; ++kb) {
          const fragb kH = *(const fragb*)&sbuf[c * 2048 + (kb * 16 + l15) * 32 + g * 8];
          const fragb kL = *(const fragb*)&sbuf[4096 + c * 2048 + (kb * 16 + l15) * 32 + g * 8];
          sacc[kb] = MFMA16(qfh[c], kH, sacc[kb]);
          sacc[kb] = MFMA16(qfh[c], kL, sacc[kb]);
          sacc[kb] = MFMA16(qfl[c], kH, sacc[kb]);
        }
      }
      // ---- scale + causal mask + online softmax ----
      float p[4][4], mx[4];
#pragma unroll
      for (int r = 0; r < 4; ++r) {
        const int qrow = qbase + 4 * g + r;
#pragma unroll
        for (int kb = 0; kb < 4; ++kb) {
          const int kc = k0 + kb * 16 + l15;
          const float x = sacc[kb][r] * 0.125f;    // 1/sqrt(64)
          p[kb][r] = (kc > qrow) ? -1e30f : x;
        }
        mx[r] = fmaxf(fmaxf(p[0][r], p[1][r]), fmaxf(p[2][r], p[3][r]));
      }
#pragma unroll
      for (int off = 8; off > 0; off >>= 1)
#pragma unroll
        for (int r = 0; r < 4; ++r)
          mx[r] = fmaxf(mx[r], __shfl_xor(mx[r], off));
#pragma unroll
      for (int r = 0; r < 4; ++r) {
        const float mnew = fmaxf(m_run[r], mx[r]);
        const float alpha = __expf(m_run[r] - mnew);
        m_run[r] = mnew;
        float rs = 0.f;
#pragma unroll
        for (int kb = 0; kb < 4; ++kb) { p[kb][r] = __expf(p[kb][r] - mnew); rs += p[kb][r]; }
#pragma unroll
        for (int off = 8; off > 0; off >>= 1) rs += __shfl_xor(rs, off);
        l_run[r] = l_run[r] * alpha + rs;
#pragma unroll
        for (int db = 0; db < 4; ++db) oacc[db][r] *= alpha;
      }
      // ---- P -> LDS (own wave strip) ----
      const int strip = 16 * w;
#pragma unroll
      for (int kb = 0; kb < 4; ++kb)
#pragma unroll
        for (int r = 0; r < 4; ++r)
          sbuf[16384 + (strip + 4 * g + r) * 72 + kb * 16 + l15] = bf16rne(p[kb][r]);
      // ---- O += P (Vh + Vl) ----
#pragma unroll
      for (int c = 0; c < 2; ++c) {
        const fragb pf = *(const fragb*)&sbuf[16384 + (strip + l15) * 72 + c * 32 + g * 8];
#pragma unroll
        for (int db = 0; db < 4; ++db) {
          const fragb vH = *(const fragb*)&sbuf[8192  + c * 2048 + (db * 16 + l15) * 32 + g * 8];
          const fragb vL = *(const fragb*)&sbuf[12288 + c * 2048 + (db * 16 + l15) * 32 + g * 8];
          oacc[db] = MFMA16(pf, vH, oacc[db]);
          oacc[db] = MFMA16(pf, vL, oacc[db]);
        }
      }
    }
  }

  // ---- epilogue: normalize, write hi/lo planes of attended [B,S,D] ----
#pragma unroll
  for (int r = 0; r < 4; ++r) {
    const float rl = 1.0f / l_run[r];
    const int s = qbase + 4 * g + r;
    const size_t base = ((size_t)b * Sc + s) * Dc + h * 64 + l15;
#pragma unroll
    for (int db = 0; db < 4; ++db) {
      unsigned short hbits, lbits;
      splitt(oacc[db][r] * rl, hbits, lbits);
      Aoh[base + db * 16] = hbits;
      Aol[base + db * 16] = lbits;
    }
  }
}

}  // namespace

extern "C" void kernel_launch(void* const* d_in, const int* in_sizes, int n_in,
                              void* d_out, int out_size, void* d_ws, size_t ws_size,
                              hipStream_t stream) {
  const float* q  = (const float*)d_in[0];
  const float* k  = (const float*)d_in[1];
  const float* v  = (const float*)d_in[2];
  // d_in[3] = causal mask (bool) — structure known, not read
  const float* wq = (const float*)d_in[4];
  const float* wk = (const float*)d_in[5];
  const float* wv = (const float*)d_in[6];
  const float* wo = (const float*)d_in[7];
  const float* bo = (const float*)d_in[8];

  unsigned short* ws = (unsigned short*)d_ws;
  const size_t NQ = (size_t)Mc * Dc;        // 3,145,728 elems per plane
  // Region 0/1: reused — X-input planes per projection, then attended planes.
  unsigned short* Xh_  = ws + 0 * NQ;
  unsigned short* Xl_  = ws + 1 * NQ;
  unsigned short* Qh_  = ws + 2 * NQ;       // [b,h,s,dk] hi/lo
  unsigned short* Ql_  = ws + 3 * NQ;
  unsigned short* Kh_  = ws + 4 * NQ;
  unsigned short* Kl_  = ws + 5 * NQ;
  unsigned short* Vth_ = ws + 6 * NQ;       // [b,h,dk,s] hi/lo
  unsigned short* Vtl_ = ws + 7 * NQ;       // total 50.33 MB (proven envelope)

  const dim3 blk(256);
  const dim3 gsplit((Mc * Dc / 8 + 255) / 256);   // 1536 blocks
  const dim3 gproj(Mc / 128, Dc / 64);            // 32 x 12
  const dim3 gattn(32, 2 * Hc);                   // 32 pairs x 24 (b,h)

  split_kernel<<<gsplit, blk, 0, stream>>>(q, Xh_, Xl_, Mc * Dc / 8);
  proj_kernel<0><<<gproj, blk, 0, stream>>>(Xh_, Xl_, wq, nullptr, Qh_, Ql_, nullptr);
  split_kernel<<<gsplit, blk, 0, stream>>>(k, Xh_, Xl_, Mc * Dc / 8);
  proj_kernel<0><<<gproj, blk, 0, stream>>>(Xh_, Xl_, wk, nullptr, Kh_, Kl_, nullptr);
  split_kernel<<<gsplit, blk, 0, stream>>>(v, Xh_, Xl_, Mc * Dc / 8);
  proj_kernel<1><<<gproj, blk, 0, stream>>>(Xh_, Xl_, wv, nullptr, Vth_, Vtl_, nullptr);
  attn_kernel<<<gattn, blk, 0, stream>>>(Qh_, Ql_, Kh_, Kl_, Vth_, Vtl_, Xh_, Xl_);
  proj_kernel<2><<<gproj, blk, 0, stream>>>(Xh_, Xl_, wo, bo, nullptr, nullptr, (float*)d_out);
}